// Round 15
// baseline (127.641 us; speedup 1.0000x reference)
//
#include <hip/hip_runtime.h>

#define D 64
#define NB 512         // nodes per dst-bucket
#define NBK_MAX 128
#define BCAP 10240     // edge capacity per bucket (avg ~8.2k)
#define EPB 4096       // edges per partition block (staged sort)

typedef __attribute__((ext_vector_type(8))) short bf16x8;   // 8 bf16 (4 VGPRs)
typedef __attribute__((ext_vector_type(4))) float f32x4;    // 4 f32 acc

__device__ __forceinline__ unsigned int bf16r(float f) {
    unsigned int u = __float_as_uint(f);
    return (u + 0x7fffu + ((u >> 16) & 1u)) >> 16;   // RNE to bf16
}
__device__ __forceinline__ float bflo(unsigned int u) { return __uint_as_float(u << 16); }
__device__ __forceinline__ float bfhi(unsigned int u) { return __uint_as_float(u & 0xffff0000u); }

// ---- P1: [0,cgrid) cvt x->bf16 ; [cgrid,+wgrid) cvt W->bf16 ;
//      rest: staged counting-sort partition of 4096 edges into buckets ------
__global__ __launch_bounds__(256) void p1_kernel(
    const float* __restrict__ x, unsigned short* __restrict__ xb, int n8,
    const float* __restrict__ W, unsigned short* __restrict__ Wb, int w8,
    const int* __restrict__ src, const int* __restrict__ dst, int n_edges,
    int* __restrict__ bcursor, int* __restrict__ bpack, int nbk,
    int cgrid, int wgrid)
{
    __shared__ int lh[NBK_MAX * 8];     // hist replicas
    __shared__ int lrb[NBK_MAX * 8];    // replica base within block-local run
    __shared__ int lsb[NBK_MAX];        // block-local run base (excl scan)
    __shared__ int lgb[NBK_MAX];        // global base (bcursor alloc)
    __shared__ int ltot[NBK_MAX];       // run length
    __shared__ int stage[EPB];          // staged packed edges (bucket order)

    int tid = threadIdx.x;
    int bi  = blockIdx.x;

    if (bi < cgrid + wgrid) {
        const float* in; unsigned short* out; int t;
        if (bi < cgrid) { in = x; out = xb; t = bi * 256 + tid; if (t >= n8) return; }
        else            { in = W; out = Wb; t = (bi - cgrid) * 256 + tid; if (t >= w8) return; }
        const float4* p = reinterpret_cast<const float4*>(in) + (size_t)t * 2;
        float4 v0 = p[0], v1 = p[1];
        uint4 o;
        o.x = bf16r(v0.x) | (bf16r(v0.y) << 16);
        o.y = bf16r(v0.z) | (bf16r(v0.w) << 16);
        o.z = bf16r(v1.x) | (bf16r(v1.y) << 16);
        o.w = bf16r(v1.z) | (bf16r(v1.w) << 16);
        reinterpret_cast<uint4*>(out)[t] = o;
        return;
    }

    // ---- partition: this block owns EPB edges ----
    for (int t = tid; t < NBK_MAX * 8; t += 256) lh[t] = 0;
    __syncthreads();

    int pb = bi - cgrid - wgrid;
    int ebase = pb * EPB;
    int r = tid & 7;
    int lo[16];

    // phase 1: histogram (16 edges/thread, coalesced int4 groups)
    #pragma unroll
    for (int k = 0; k < 4; ++k) {
        int e4 = ebase + (tid + k * 256) * 4;
        if (e4 + 4 <= n_edges) {
            int4 dd = *reinterpret_cast<const int4*>(dst + e4);
            lo[k * 4 + 0] = atomicAdd(&lh[((dd.x >> 9) << 3) | r], 1);
            lo[k * 4 + 1] = atomicAdd(&lh[((dd.y >> 9) << 3) | r], 1);
            lo[k * 4 + 2] = atomicAdd(&lh[((dd.z >> 9) << 3) | r], 1);
            lo[k * 4 + 3] = atomicAdd(&lh[((dd.w >> 9) << 3) | r], 1);
        } else {
            #pragma unroll
            for (int j = 0; j < 4; ++j)
                if (e4 + j < n_edges)
                    lo[k * 4 + j] = atomicAdd(&lh[((dst[e4 + j] >> 9) << 3) | r], 1);
        }
    }
    __syncthreads();

    // per-bucket totals + replica bases + global alloc
    if (tid < NBK_MAX) {
        int tot = 0, pbs[8];
        #pragma unroll
        for (int rr = 0; rr < 8; ++rr) { pbs[rr] = tot; tot += lh[(tid << 3) | rr]; }
        #pragma unroll
        for (int rr = 0; rr < 8; ++rr) lrb[(tid << 3) | rr] = pbs[rr];
        ltot[tid] = tot;
        lsb[tid] = tot;                 // will be scanned in place
        if (tid < nbk && tot > 0) lgb[tid] = atomicAdd(&bcursor[tid], tot);
    }
    __syncthreads();
    // block-local exclusive scan of bucket totals (128 entries)
    for (int off = 1; off < NBK_MAX; off <<= 1) {
        int v = 0;
        if (tid < NBK_MAX && tid >= off) v = lsb[tid - off];
        __syncthreads();
        if (tid < NBK_MAX) lsb[tid] += v;
        __syncthreads();
    }
    // lsb now inclusive; convert to exclusive on read (lsb[bk]-ltot[bk])

    // phase 2: reread edges (L2-hot), stage into bucket order
    #pragma unroll
    for (int k = 0; k < 4; ++k) {
        int e4 = ebase + (tid + k * 256) * 4;
        if (e4 + 4 <= n_edges) {
            int4 dd = *reinterpret_cast<const int4*>(dst + e4);
            int4 ss = *reinterpret_cast<const int4*>(src + e4);
            int bks[4] = {dd.x >> 9, dd.y >> 9, dd.z >> 9, dd.w >> 9};
            int dvs[4] = {dd.x, dd.y, dd.z, dd.w};
            int svs[4] = {ss.x, ss.y, ss.z, ss.w};
            #pragma unroll
            for (int j = 0; j < 4; ++j) {
                int bk = bks[j];
                int pos = (lsb[bk] - ltot[bk]) + lrb[(bk << 3) | r] + lo[k * 4 + j];
                stage[pos] = svs[j] | ((dvs[j] & (NB - 1)) << 20);
            }
        } else {
            #pragma unroll
            for (int j = 0; j < 4; ++j) {
                if (e4 + j < n_edges) {
                    int dv = dst[e4 + j];
                    int bk = dv >> 9;
                    int pos = (lsb[bk] - ltot[bk]) + lrb[(bk << 3) | r] + lo[k * 4 + j];
                    stage[pos] = src[e4 + j] | ((dv & (NB - 1)) << 20);
                }
            }
        }
    }
    __syncthreads();

    // phase 3: copy each bucket run to bpack (coalesced contiguous chunks)
    for (int bk = 0; bk < nbk; ++bk) {
        int len = ltot[bk];
        if (len == 0) continue;
        int sb = lsb[bk] - len;
        int gb = lgb[bk];
        int* dstp = bpack + (size_t)bk * BCAP + gb;
        for (int i = tid; i < len; i += 256) dstp[i] = stage[sb + i];
    }
}

// ---- P2: per-bucket CSR (LDS count -> scan -> rp, then LDS-cursor fill) ---
__global__ __launch_bounds__(512) void p2_kernel(
    const int* __restrict__ bcursor, const int* __restrict__ bpack,
    int* __restrict__ rp, int* __restrict__ csr,
    int n_nodes, int n_edges, int nbk)
{
    __shared__ int sz[NBK_MAX];
    __shared__ int lh[NB];
    __shared__ int ls[NB];

    int tid = threadIdx.x;
    int bk  = blockIdx.x;

    for (int t = tid; t < NBK_MAX; t += 512) sz[t] = (t < nbk) ? bcursor[t] : 0;
    lh[tid] = 0;
    __syncthreads();
    if (tid == 0) {                      // tiny serial prefix of nbk sizes
        int a = 0;
        for (int i = 0; i < nbk; ++i) { int c = sz[i]; sz[i] = a; a += c; }
    }
    __syncthreads();

    int cnt      = bcursor[bk];
    int csr_base = sz[bk];
    const int* bp = bpack + (size_t)bk * BCAP;

    // count
    for (int i = tid; i < cnt; i += 512) atomicAdd(&lh[bp[i] >> 20], 1);
    __syncthreads();

    // exclusive scan of 512 bins
    int v = lh[tid];
    ls[tid] = v;
    __syncthreads();
    for (int off = 1; off < 512; off <<= 1) {
        int t = (tid >= off) ? ls[tid - off] : 0;
        __syncthreads();
        ls[tid] += t;
        __syncthreads();
    }
    int ex = ls[tid] - v;

    int node = bk * NB + tid;
    if (node < n_nodes) rp[node] = csr_base + ex;
    if (bk == nbk - 1 && tid == 0) rp[n_nodes] = n_edges;
    __syncthreads();

    lh[tid] = ex;                        // reuse as cursor
    __syncthreads();
    for (int i = tid; i < cnt; i += 512) {
        int p = bp[i];
        int pos = atomicAdd(&lh[p >> 20], 1);
        csr[csr_base + pos] = p & 0xFFFFF;
    }
}

// ---------------- fallback tap (f32 in) ------------------------------------
__global__ __launch_bounds__(256) void tap_kernel(
    const float* __restrict__ xin, const float* __restrict__ W,
    const float* __restrict__ b, float* __restrict__ y,
    int n_nodes, int first)
{
    __shared__ float Wt[D * (D + 1)];
    __shared__ float bs[D];
    __shared__ float xs[4][D];

    int tid = threadIdx.x;
    for (int t = tid; t < D * D; t += 256) {
        int j = t >> 6, i = t & 63;
        Wt[i * (D + 1) + j] = W[t];
    }
    if (tid < D) bs[tid] = b[tid];

    int rl = tid >> 6;
    int j  = tid & 63;
    int row = blockIdx.x * 4 + rl;
    if (row < n_nodes) xs[rl][j] = xin[(size_t)row * D + j];
    __syncthreads();

    if (row >= n_nodes) return;

    float acc = bs[j];
    #pragma unroll 8
    for (int i = 0; i < D; ++i)
        acc = fmaf(xs[rl][i], Wt[i * (D + 1) + j], acc);

    float* yp = y + (size_t)row * D + j;
    *yp = first ? acc : (*yp + acc);
}

// ------- MFMA fused tap: y = [X0|X1|X2|X3](bf16) @ Wcat^T + sum_b ----------
__global__ __launch_bounds__(256) void mfma_tap_kernel(
    const unsigned short* __restrict__ X0, const unsigned short* __restrict__ X1,
    const unsigned short* __restrict__ X2, const unsigned short* __restrict__ X3,
    const unsigned short* __restrict__ Wb, const float* __restrict__ b,
    float* __restrict__ y, int n_tiles)
{
    int wv   = threadIdx.x >> 6;
    int lane = threadIdx.x & 63;
    int tile = blockIdx.x * 4 + wv;
    if (tile >= n_tiles) return;

    int col = lane & 15;
    int kg  = lane >> 4;          // K-group 0..3

    f32x4 acc[4];
    #pragma unroll
    for (int jt = 0; jt < 4; ++jt) {
        int c = jt * 16 + col;
        float bias = b[c] + b[64 + c] + b[128 + c] + b[192 + c];
        acc[jt] = (f32x4){bias, bias, bias, bias};
    }

    const unsigned short* Xs[4] = {X0, X1, X2, X3};
    size_t arow = (size_t)(tile * 16 + col) * D + kg * 8;

    #pragma unroll
    for (int m = 0; m < 4; ++m) {
        const unsigned short* Xm = Xs[m];
        #pragma unroll
        for (int s = 0; s < 2; ++s) {
            bf16x8 a = *reinterpret_cast<const bf16x8*>(Xm + arow + s * 32);
            #pragma unroll
            for (int jt = 0; jt < 4; ++jt) {
                bf16x8 bb = *reinterpret_cast<const bf16x8*>(
                    Wb + m * 4096 + (jt * 16 + col) * D + s * 32 + kg * 8);
                acc[jt] = __builtin_amdgcn_mfma_f32_16x16x32_bf16(a, bb, acc[jt], 0, 0, 0);
            }
        }
    }

    #pragma unroll
    for (int jt = 0; jt < 4; ++jt) {
        #pragma unroll
        for (int r = 0; r < 4; ++r) {
            int row = kg * 4 + r;
            y[(size_t)(tile * 16 + row) * D + jt * 16 + col] = acc[jt][r];
        }
    }
}

// ------- pull (bf16): xout[v] = bf16( sum_{e:dst=v} xin[src[e]] ) ----------
// 2 nodes/wave; 8-lane groups x uint4(16B) => one vmem instr covers 8 rows.
__global__ __launch_bounds__(256) void pull_bf16_kernel(
    const unsigned short* __restrict__ xin, unsigned short* __restrict__ xout,
    const int* __restrict__ rp, const int* __restrict__ csr, int n_nodes)
{
    int tid  = threadIdx.x;
    int wid  = (blockIdx.x * 256 + tid) >> 6;
    int lane = tid & 63;
    int half = lane >> 5;        // node within wave
    int hl   = lane & 31;        // lane within half
    int hb   = half << 5;        // half base
    int g    = (lane >> 3) & 3;  // edge-group (4 per half)
    int cl   = lane & 7;         // uint4 chunk within 128B row
    int node = wid * 2 + half;

    int beg = 0, end = 0;
    if (node < n_nodes) { beg = rp[node]; end = rp[node + 1]; }
    int cnt  = end - beg;
    int cntO = __shfl_xor(cnt, 32);
    int maxcnt = cnt > cntO ? cnt : cntO;   // wave-uniform

    const uint4* xu = reinterpret_cast<const uint4*>(xin);
    float a0 = 0.f, a1 = 0.f, a2 = 0.f, a3 = 0.f;
    float a4 = 0.f, a5 = 0.f, a6 = 0.f, a7 = 0.f;

    for (int base = 0; base < maxcnt; base += 32) {
        int t = base + hl;
        int idx = (t < cnt) ? csr[beg + t] : 0;     // coalesced per half-wave
        #pragma unroll
        for (int ii = 0; ii < 4; ++ii) {            // edges 4*ii+g = 0..15
            int el = 4 * ii + g;
            int s = __shfl(idx, hb + el);
            if (base + el < cnt) {
                uint4 u = xu[(size_t)s * 8 + cl];   // 128B row per 8 lanes
                a0 += bflo(u.x); a1 += bfhi(u.x);
                a2 += bflo(u.y); a3 += bfhi(u.y);
                a4 += bflo(u.z); a5 += bfhi(u.z);
                a6 += bflo(u.w); a7 += bfhi(u.w);
            }
        }
        if (maxcnt - base > 16) {
            #pragma unroll
            for (int ii = 4; ii < 8; ++ii) {        // edges 16..31
                int el = 4 * ii + g;
                int s = __shfl(idx, hb + el);
                if (base + el < cnt) {
                    uint4 u = xu[(size_t)s * 8 + cl];
                    a0 += bflo(u.x); a1 += bfhi(u.x);
                    a2 += bflo(u.y); a3 += bfhi(u.y);
                    a4 += bflo(u.z); a5 += bfhi(u.z);
                    a6 += bflo(u.w); a7 += bfhi(u.w);
                }
            }
        }
    }

    // reduce across the 4 edge-groups within each half (xor 8, then 16)
    a0 += __shfl_xor(a0, 8);  a1 += __shfl_xor(a1, 8);
    a2 += __shfl_xor(a2, 8);  a3 += __shfl_xor(a3, 8);
    a4 += __shfl_xor(a4, 8);  a5 += __shfl_xor(a5, 8);
    a6 += __shfl_xor(a6, 8);  a7 += __shfl_xor(a7, 8);
    a0 += __shfl_xor(a0, 16); a1 += __shfl_xor(a1, 16);
    a2 += __shfl_xor(a2, 16); a3 += __shfl_xor(a3, 16);
    a4 += __shfl_xor(a4, 16); a5 += __shfl_xor(a5, 16);
    a6 += __shfl_xor(a6, 16); a7 += __shfl_xor(a7, 16);

    if (node < n_nodes && g == 0) {
        uint4 o;
        o.x = bf16r(a0) | (bf16r(a1) << 16);
        o.y = bf16r(a2) | (bf16r(a3) << 16);
        o.z = bf16r(a4) | (bf16r(a5) << 16);
        o.w = bf16r(a6) | (bf16r(a7) << 16);
        reinterpret_cast<uint4*>(xout)[(size_t)node * 8 + cl] = o;
    }
}

// ---------------- fallback (atomic push) if ws too small -------------------
__global__ __launch_bounds__(256) void scatter_kernel(
    const float* __restrict__ xin, float* __restrict__ xout,
    const int* __restrict__ src, const int* __restrict__ dst, int n_edges)
{
    int t = blockIdx.x * blockDim.x + threadIdx.x;
    int e = t >> 4;
    if (e >= n_edges) return;
    int c = (t & 15) * 4;
    int s = src[e];
    int d = dst[e];
    const float4 v = *reinterpret_cast<const float4*>(xin + (size_t)s * D + c);
    float* o = xout + (size_t)d * D + c;
    atomicAdd(o + 0, v.x);
    atomicAdd(o + 1, v.y);
    atomicAdd(o + 2, v.z);
    atomicAdd(o + 3, v.w);
}

extern "C" void kernel_launch(void* const* d_in, const int* in_sizes, int n_in,
                              void* d_out, int out_size, void* d_ws, size_t ws_size,
                              hipStream_t stream) {
    const float* x  = (const float*)d_in[0];
    const int*   ei = (const int*)d_in[1];
    const float* W  = (const float*)d_in[2];
    const float* b  = (const float*)d_in[3];
    float* y = (float*)d_out;

    int n_nodes = in_sizes[0] / D;   // 50000
    int n_edges = in_sizes[1] / 2;   // 800000
    const int* src = ei;
    const int* dst = ei + n_edges;

    int nbk = (n_nodes + NB - 1) / NB;               // 98

    size_t bufElems = (size_t)n_nodes * D;          // 3.2M
    unsigned short* xb = (unsigned short*)d_ws;     // bf16 x
    unsigned short* Ab = xb + bufElems;             // bf16 agg1
    unsigned short* Bb = Ab + bufElems;             // bf16 agg2
    unsigned short* Cb = Bb + bufElems;             // bf16 agg3
    unsigned short* Wb = Cb + bufElems;             // bf16 W (4*64*64)
    int* bcursor = (int*)(Wb + 4 * D * D);          // NBK_MAX
    int* bpack   = bcursor + NBK_MAX;               // nbk*BCAP packed edges
    int* rp      = bpack + (size_t)nbk * BCAP;      // n_nodes+1 (+pad)
    int* csr     = rp + n_nodes + 64;               // n_edges

    size_t needed = (char*)(csr + n_edges) - (char*)d_ws;

    dim3 tb(256);
    dim3 tg((n_nodes + 3) / 4);
    int n8     = (int)(bufElems / 8);
    int cgrid  = (n8 + 255) / 256;
    int w8     = 4 * D * D / 8;                 // 2048
    int wgrid  = (w8 + 255) / 256;              // 8
    int eb     = (n_edges + EPB - 1) / EPB;     // 196
    int pgrid  = ((n_nodes + 1) / 2 + 3) / 4;   // 2 nodes/wave, 4 waves/block
    int n_tiles = (n_nodes + 15) / 16;          // 3125
    int mgrid  = (n_tiles + 3) / 4;

    if (needed <= ws_size && (n_nodes & 15) == 0 && nbk <= NBK_MAX) {
        // ---- CSR build: P1 (fused cvt + staged partition) then P2 ----
        hipMemsetAsync(bcursor, 0, NBK_MAX * sizeof(int), stream);
        p1_kernel<<<cgrid + wgrid + eb, tb, 0, stream>>>(
            x, xb, n8, W, Wb, w8, src, dst, n_edges, bcursor, bpack, nbk,
            cgrid, wgrid);
        p2_kernel<<<nbk, 512, 0, stream>>>(bcursor, bpack, rp, csr,
                                           n_nodes, n_edges, nbk);

        // ---- shift chain back-to-back (L2-hot producer->consumer) ----
        pull_bf16_kernel<<<pgrid, tb, 0, stream>>>(xb, Ab, rp, csr, n_nodes);
        pull_bf16_kernel<<<pgrid, tb, 0, stream>>>(Ab, Bb, rp, csr, n_nodes);
        pull_bf16_kernel<<<pgrid, tb, 0, stream>>>(Bb, Cb, rp, csr, n_nodes);

        // ---- tap phase: single MFMA GEMM  y = Xcat @ Wcat^T + bsum ----
        mfma_tap_kernel<<<mgrid, tb, 0, stream>>>(xb, Ab, Bb, Cb, Wb, b, y, n_tiles);
    } else {
        // ---- fallback: atomic push path (f32) ----
        float* A = (float*)d_ws;
        float* B = A + bufElems;
        size_t bufBytes = bufElems * sizeof(float);
        int sgrid = (n_edges * 16 + 255) / 256;
        hipMemsetAsync(A, 0, bufBytes, stream);
        hipMemsetAsync(B, 0, bufBytes, stream);
        tap_kernel<<<tg, tb, 0, stream>>>(x, W, b, y, n_nodes, 1);
        scatter_kernel<<<sgrid, tb, 0, stream>>>(x, A, src, dst, n_edges);
        tap_kernel<<<tg, tb, 0, stream>>>(A, W + D * D, b + D, y, n_nodes, 0);
        scatter_kernel<<<sgrid, tb, 0, stream>>>(A, B, src, dst, n_edges);
        hipMemsetAsync(A, 0, bufBytes, stream);
        tap_kernel<<<tg, tb, 0, stream>>>(B, W + 2 * D * D, b + 2 * D, y, n_nodes, 0);
        scatter_kernel<<<sgrid, tb, 0, stream>>>(B, A, src, dst, n_edges);
        tap_kernel<<<tg, tb, 0, stream>>>(A, W + 3 * D * D, b + 3 * D, y, n_nodes, 0);
    }
}

// Round 16
// 117.717 us; speedup vs baseline: 1.0843x; 1.0843x over previous
//
#include <hip/hip_runtime.h>

#define D 64
#define NB 512         // nodes per dst-bucket
#define NBK_MAX 128
#define BCAP 10240     // edge capacity per bucket (avg ~8.2k)

typedef __attribute__((ext_vector_type(8))) short bf16x8;   // 8 bf16 (4 VGPRs)
typedef __attribute__((ext_vector_type(4))) float f32x4;    // 4 f32 acc

__device__ __forceinline__ unsigned int bf16r(float f) {
    unsigned int u = __float_as_uint(f);
    return (u + 0x7fffu + ((u >> 16) & 1u)) >> 16;   // RNE to bf16
}
__device__ __forceinline__ float bflo(unsigned int u) { return __uint_as_float(u << 16); }
__device__ __forceinline__ float bfhi(unsigned int u) { return __uint_as_float(u & 0xffff0000u); }

// ---- P1: [0,cgrid) cvt x->bf16 ; [cgrid,+wgrid) cvt W->bf16 ;
//      rest: partition edges into 512-node dst-buckets via LDS histogram ----
__global__ __launch_bounds__(256) void p1_kernel(
    const float* __restrict__ x, unsigned short* __restrict__ xb, int n8,
    const float* __restrict__ W, unsigned short* __restrict__ Wb, int w8,
    const int* __restrict__ src, const int* __restrict__ dst, int n_edges,
    int* __restrict__ bcursor, int* __restrict__ bpack, int nbk,
    int cgrid, int wgrid)
{
    __shared__ int lh[NBK_MAX * 8];     // 8 replicas per bucket
    __shared__ int lbase[NBK_MAX * 8];

    int tid = threadIdx.x;
    int bi  = blockIdx.x;

    if (bi < cgrid + wgrid) {
        const float* in; unsigned short* out; int t;
        if (bi < cgrid) { in = x; out = xb; t = bi * 256 + tid; if (t >= n8) return; }
        else            { in = W; out = Wb; t = (bi - cgrid) * 256 + tid; if (t >= w8) return; }
        const float4* p = reinterpret_cast<const float4*>(in) + (size_t)t * 2;
        float4 v0 = p[0], v1 = p[1];
        uint4 o;
        o.x = bf16r(v0.x) | (bf16r(v0.y) << 16);
        o.y = bf16r(v0.z) | (bf16r(v0.w) << 16);
        o.z = bf16r(v1.x) | (bf16r(v1.y) << 16);
        o.w = bf16r(v1.z) | (bf16r(v1.w) << 16);
        reinterpret_cast<uint4*>(out)[t] = o;
        return;
    }

    // ---- partition: this block owns 1024 edges ----
    for (int t = tid; t < NBK_MAX * 8; t += 256) lh[t] = 0;
    __syncthreads();

    int pb = bi - cgrid - wgrid;
    int e4 = pb * 1024 + tid * 4;
    int r  = tid & 7;

    int dv[4], sv[4], bk[4], lo[4];
    bool ok[4];
    if (e4 + 4 <= n_edges) {
        int4 dd = *reinterpret_cast<const int4*>(dst + e4);
        int4 ss = *reinterpret_cast<const int4*>(src + e4);
        dv[0] = dd.x; dv[1] = dd.y; dv[2] = dd.z; dv[3] = dd.w;
        sv[0] = ss.x; sv[1] = ss.y; sv[2] = ss.z; sv[3] = ss.w;
        ok[0] = ok[1] = ok[2] = ok[3] = true;
    } else {
        #pragma unroll
        for (int j = 0; j < 4; ++j) {
            ok[j] = (e4 + j < n_edges);
            dv[j] = ok[j] ? dst[e4 + j] : 0;
            sv[j] = ok[j] ? src[e4 + j] : 0;
        }
    }
    #pragma unroll
    for (int j = 0; j < 4; ++j) {
        bk[j] = dv[j] >> 9;
        if (ok[j]) lo[j] = atomicAdd(&lh[(bk[j] << 3) | r], 1);
    }
    __syncthreads();

    if (tid < nbk) {
        int tot = 0, pbs[8];
        #pragma unroll
        for (int rr = 0; rr < 8; ++rr) { pbs[rr] = tot; tot += lh[(tid << 3) | rr]; }
        int gb = atomicAdd(&bcursor[tid], tot);      // nbk global atomics/block
        #pragma unroll
        for (int rr = 0; rr < 8; ++rr) lbase[(tid << 3) | rr] = gb + pbs[rr];
    }
    __syncthreads();

    #pragma unroll
    for (int j = 0; j < 4; ++j) {
        if (ok[j]) {
            int pos = lbase[(bk[j] << 3) | r] + lo[j];
            bpack[bk[j] * BCAP + pos] = sv[j] | ((dv[j] & (NB - 1)) << 20);
        }
    }
}

// ---- P2: per-bucket CSR (LDS count -> scan -> rp, then LDS-cursor fill) ---
__global__ __launch_bounds__(512) void p2_kernel(
    const int* __restrict__ bcursor, const int* __restrict__ bpack,
    int* __restrict__ rp, int* __restrict__ csr,
    int n_nodes, int n_edges, int nbk)
{
    __shared__ int sz[NBK_MAX];
    __shared__ int lh[NB];
    __shared__ int ls[NB];

    int tid = threadIdx.x;
    int bk  = blockIdx.x;

    for (int t = tid; t < NBK_MAX; t += 512) sz[t] = (t < nbk) ? bcursor[t] : 0;
    lh[tid] = 0;
    __syncthreads();
    if (tid == 0) {                      // tiny serial prefix of nbk sizes
        int a = 0;
        for (int i = 0; i < nbk; ++i) { int c = sz[i]; sz[i] = a; a += c; }
    }
    __syncthreads();

    int cnt      = bcursor[bk];
    int csr_base = sz[bk];
    const int* bp = bpack + (size_t)bk * BCAP;

    // count
    for (int i = tid; i < cnt; i += 512) atomicAdd(&lh[bp[i] >> 20], 1);
    __syncthreads();

    // exclusive scan of 512 bins
    int v = lh[tid];
    ls[tid] = v;
    __syncthreads();
    for (int off = 1; off < 512; off <<= 1) {
        int t = (tid >= off) ? ls[tid - off] : 0;
        __syncthreads();
        ls[tid] += t;
        __syncthreads();
    }
    int ex = ls[tid] - v;

    int node = bk * NB + tid;
    if (node < n_nodes) rp[node] = csr_base + ex;
    if (bk == nbk - 1 && tid == 0) rp[n_nodes] = n_edges;
    __syncthreads();

    lh[tid] = ex;                        // reuse as cursor
    __syncthreads();
    for (int i = tid; i < cnt; i += 512) {
        int p = bp[i];
        int pos = atomicAdd(&lh[p >> 20], 1);
        csr[csr_base + pos] = p & 0xFFFFF;
    }
}

// ---------------- fallback tap (f32 in) ------------------------------------
__global__ __launch_bounds__(256) void tap_kernel(
    const float* __restrict__ xin, const float* __restrict__ W,
    const float* __restrict__ b, float* __restrict__ y,
    int n_nodes, int first)
{
    __shared__ float Wt[D * (D + 1)];
    __shared__ float bs[D];
    __shared__ float xs[4][D];

    int tid = threadIdx.x;
    for (int t = tid; t < D * D; t += 256) {
        int j = t >> 6, i = t & 63;
        Wt[i * (D + 1) + j] = W[t];
    }
    if (tid < D) bs[tid] = b[tid];

    int rl = tid >> 6;
    int j  = tid & 63;
    int row = blockIdx.x * 4 + rl;
    if (row < n_nodes) xs[rl][j] = xin[(size_t)row * D + j];
    __syncthreads();

    if (row >= n_nodes) return;

    float acc = bs[j];
    #pragma unroll 8
    for (int i = 0; i < D; ++i)
        acc = fmaf(xs[rl][i], Wt[i * (D + 1) + j], acc);

    float* yp = y + (size_t)row * D + j;
    *yp = first ? acc : (*yp + acc);
}

// ------- MFMA fused tap: y = [X0|X1|X2|X3](bf16) @ Wcat^T + sum_b ----------
__global__ __launch_bounds__(256) void mfma_tap_kernel(
    const unsigned short* __restrict__ X0, const unsigned short* __restrict__ X1,
    const unsigned short* __restrict__ X2, const unsigned short* __restrict__ X3,
    const unsigned short* __restrict__ Wb, const float* __restrict__ b,
    float* __restrict__ y, int n_tiles)
{
    int wv   = threadIdx.x >> 6;
    int lane = threadIdx.x & 63;
    int tile = blockIdx.x * 4 + wv;
    if (tile >= n_tiles) return;

    int col = lane & 15;
    int kg  = lane >> 4;          // K-group 0..3

    f32x4 acc[4];
    #pragma unroll
    for (int jt = 0; jt < 4; ++jt) {
        int c = jt * 16 + col;
        float bias = b[c] + b[64 + c] + b[128 + c] + b[192 + c];
        acc[jt] = (f32x4){bias, bias, bias, bias};
    }

    const unsigned short* Xs[4] = {X0, X1, X2, X3};
    size_t arow = (size_t)(tile * 16 + col) * D + kg * 8;

    #pragma unroll
    for (int m = 0; m < 4; ++m) {
        const unsigned short* Xm = Xs[m];
        #pragma unroll
        for (int s = 0; s < 2; ++s) {
            bf16x8 a = *reinterpret_cast<const bf16x8*>(Xm + arow + s * 32);
            #pragma unroll
            for (int jt = 0; jt < 4; ++jt) {
                bf16x8 bb = *reinterpret_cast<const bf16x8*>(
                    Wb + m * 4096 + (jt * 16 + col) * D + s * 32 + kg * 8);
                acc[jt] = __builtin_amdgcn_mfma_f32_16x16x32_bf16(a, bb, acc[jt], 0, 0, 0);
            }
        }
    }

    #pragma unroll
    for (int jt = 0; jt < 4; ++jt) {
        #pragma unroll
        for (int r = 0; r < 4; ++r) {
            int row = kg * 4 + r;
            y[(size_t)(tile * 16 + row) * D + jt * 16 + col] = acc[jt][r];
        }
    }
}

// ------- pull (bf16): xout[v] = bf16( sum_{e:dst=v} xin[src[e]] ) ----------
// 2 nodes/wave; 8-lane groups x uint4(16B) => one vmem instr covers 8 rows.
__global__ __launch_bounds__(256) void pull_bf16_kernel(
    const unsigned short* __restrict__ xin, unsigned short* __restrict__ xout,
    const int* __restrict__ rp, const int* __restrict__ csr, int n_nodes)
{
    int tid  = threadIdx.x;
    int wid  = (blockIdx.x * 256 + tid) >> 6;
    int lane = tid & 63;
    int half = lane >> 5;        // node within wave
    int hl   = lane & 31;        // lane within half
    int hb   = half << 5;        // half base
    int g    = (lane >> 3) & 3;  // edge-group (4 per half)
    int cl   = lane & 7;         // uint4 chunk within 128B row
    int node = wid * 2 + half;

    int beg = 0, end = 0;
    if (node < n_nodes) { beg = rp[node]; end = rp[node + 1]; }
    int cnt  = end - beg;
    int cntO = __shfl_xor(cnt, 32);
    int maxcnt = cnt > cntO ? cnt : cntO;   // wave-uniform

    const uint4* xu = reinterpret_cast<const uint4*>(xin);
    float a0 = 0.f, a1 = 0.f, a2 = 0.f, a3 = 0.f;
    float a4 = 0.f, a5 = 0.f, a6 = 0.f, a7 = 0.f;

    for (int base = 0; base < maxcnt; base += 32) {
        int t = base + hl;
        int idx = (t < cnt) ? csr[beg + t] : 0;     // coalesced per half-wave
        #pragma unroll
        for (int ii = 0; ii < 4; ++ii) {            // edges 4*ii+g = 0..15
            int el = 4 * ii + g;
            int s = __shfl(idx, hb + el);
            if (base + el < cnt) {
                uint4 u = xu[(size_t)s * 8 + cl];   // 128B row per 8 lanes
                a0 += bflo(u.x); a1 += bfhi(u.x);
                a2 += bflo(u.y); a3 += bfhi(u.y);
                a4 += bflo(u.z); a5 += bfhi(u.z);
                a6 += bflo(u.w); a7 += bfhi(u.w);
            }
        }
        if (maxcnt - base > 16) {
            #pragma unroll
            for (int ii = 4; ii < 8; ++ii) {        // edges 16..31
                int el = 4 * ii + g;
                int s = __shfl(idx, hb + el);
                if (base + el < cnt) {
                    uint4 u = xu[(size_t)s * 8 + cl];
                    a0 += bflo(u.x); a1 += bfhi(u.x);
                    a2 += bflo(u.y); a3 += bfhi(u.y);
                    a4 += bflo(u.z); a5 += bfhi(u.z);
                    a6 += bflo(u.w); a7 += bfhi(u.w);
                }
            }
        }
    }

    // reduce across the 4 edge-groups within each half (xor 8, then 16)
    a0 += __shfl_xor(a0, 8);  a1 += __shfl_xor(a1, 8);
    a2 += __shfl_xor(a2, 8);  a3 += __shfl_xor(a3, 8);
    a4 += __shfl_xor(a4, 8);  a5 += __shfl_xor(a5, 8);
    a6 += __shfl_xor(a6, 8);  a7 += __shfl_xor(a7, 8);
    a0 += __shfl_xor(a0, 16); a1 += __shfl_xor(a1, 16);
    a2 += __shfl_xor(a2, 16); a3 += __shfl_xor(a3, 16);
    a4 += __shfl_xor(a4, 16); a5 += __shfl_xor(a5, 16);
    a6 += __shfl_xor(a6, 16); a7 += __shfl_xor(a7, 16);

    if (node < n_nodes && g == 0) {
        uint4 o;
        o.x = bf16r(a0) | (bf16r(a1) << 16);
        o.y = bf16r(a2) | (bf16r(a3) << 16);
        o.z = bf16r(a4) | (bf16r(a5) << 16);
        o.w = bf16r(a6) | (bf16r(a7) << 16);
        reinterpret_cast<uint4*>(xout)[(size_t)node * 8 + cl] = o;
    }
}

// ---------------- fallback (atomic push) if ws too small -------------------
__global__ __launch_bounds__(256) void scatter_kernel(
    const float* __restrict__ xin, float* __restrict__ xout,
    const int* __restrict__ src, const int* __restrict__ dst, int n_edges)
{
    int t = blockIdx.x * blockDim.x + threadIdx.x;
    int e = t >> 4;
    if (e >= n_edges) return;
    int c = (t & 15) * 4;
    int s = src[e];
    int d = dst[e];
    const float4 v = *reinterpret_cast<const float4*>(xin + (size_t)s * D + c);
    float* o = xout + (size_t)d * D + c;
    atomicAdd(o + 0, v.x);
    atomicAdd(o + 1, v.y);
    atomicAdd(o + 2, v.z);
    atomicAdd(o + 3, v.w);
}

extern "C" void kernel_launch(void* const* d_in, const int* in_sizes, int n_in,
                              void* d_out, int out_size, void* d_ws, size_t ws_size,
                              hipStream_t stream) {
    const float* x  = (const float*)d_in[0];
    const int*   ei = (const int*)d_in[1];
    const float* W  = (const float*)d_in[2];
    const float* b  = (const float*)d_in[3];
    float* y = (float*)d_out;

    int n_nodes = in_sizes[0] / D;   // 50000
    int n_edges = in_sizes[1] / 2;   // 800000
    const int* src = ei;
    const int* dst = ei + n_edges;

    int nbk = (n_nodes + NB - 1) / NB;               // 98

    size_t bufElems = (size_t)n_nodes * D;          // 3.2M
    unsigned short* xb = (unsigned short*)d_ws;     // bf16 x
    unsigned short* Ab = xb + bufElems;             // bf16 agg1
    unsigned short* Bb = Ab + bufElems;             // bf16 agg2
    unsigned short* Cb = Bb + bufElems;             // bf16 agg3
    unsigned short* Wb = Cb + bufElems;             // bf16 W (4*64*64)
    int* bcursor = (int*)(Wb + 4 * D * D);          // NBK_MAX
    int* bpack   = bcursor + NBK_MAX;               // nbk*BCAP packed edges
    int* rp      = bpack + (size_t)nbk * BCAP;      // n_nodes+1 (+pad)
    int* csr     = rp + n_nodes + 64;               // n_edges

    size_t needed = (char*)(csr + n_edges) - (char*)d_ws;

    dim3 tb(256);
    dim3 tg((n_nodes + 3) / 4);
    int n8     = (int)(bufElems / 8);
    int cgrid  = (n8 + 255) / 256;
    int w8     = 4 * D * D / 8;                 // 2048
    int wgrid  = (w8 + 255) / 256;              // 8
    int eb     = (n_edges + 1023) / 1024;       // 782
    int pgrid  = ((n_nodes + 1) / 2 + 3) / 4;   // 2 nodes/wave, 4 waves/block
    int n_tiles = (n_nodes + 15) / 16;          // 3125
    int mgrid  = (n_tiles + 3) / 4;

    if (needed <= ws_size && (n_nodes & 15) == 0 && nbk <= NBK_MAX) {
        // ---- CSR build: P1 (fused cvt + bucket partition) then P2 ----
        hipMemsetAsync(bcursor, 0, NBK_MAX * sizeof(int), stream);
        p1_kernel<<<cgrid + wgrid + eb, tb, 0, stream>>>(
            x, xb, n8, W, Wb, w8, src, dst, n_edges, bcursor, bpack, nbk,
            cgrid, wgrid);
        p2_kernel<<<nbk, 512, 0, stream>>>(bcursor, bpack, rp, csr,
                                           n_nodes, n_edges, nbk);

        // ---- shift chain back-to-back (L2-hot producer->consumer) ----
        pull_bf16_kernel<<<pgrid, tb, 0, stream>>>(xb, Ab, rp, csr, n_nodes);
        pull_bf16_kernel<<<pgrid, tb, 0, stream>>>(Ab, Bb, rp, csr, n_nodes);
        pull_bf16_kernel<<<pgrid, tb, 0, stream>>>(Bb, Cb, rp, csr, n_nodes);

        // ---- tap phase: single MFMA GEMM  y = Xcat @ Wcat^T + bsum ----
        mfma_tap_kernel<<<mgrid, tb, 0, stream>>>(xb, Ab, Bb, Cb, Wb, b, y, n_tiles);
    } else {
        // ---- fallback: atomic push path (f32) ----
        float* A = (float*)d_ws;
        float* B = A + bufElems;
        size_t bufBytes = bufElems * sizeof(float);
        int sgrid = (n_edges * 16 + 255) / 256;
        hipMemsetAsync(A, 0, bufBytes, stream);
        hipMemsetAsync(B, 0, bufBytes, stream);
        tap_kernel<<<tg, tb, 0, stream>>>(x, W, b, y, n_nodes, 1);
        scatter_kernel<<<sgrid, tb, 0, stream>>>(x, A, src, dst, n_edges);
        tap_kernel<<<tg, tb, 0, stream>>>(A, W + D * D, b + D, y, n_nodes, 0);
        scatter_kernel<<<sgrid, tb, 0, stream>>>(A, B, src, dst, n_edges);
        hipMemsetAsync(A, 0, bufBytes, stream);
        tap_kernel<<<tg, tb, 0, stream>>>(B, W + 2 * D * D, b + 2 * D, y, n_nodes, 0);
        scatter_kernel<<<sgrid, tb, 0, stream>>>(B, A, src, dst, n_edges);
        tap_kernel<<<tg, tb, 0, stream>>>(A, W + 3 * D * D, b + 3 * D, y, n_nodes, 0);
    }
}